// Round 3
// baseline (112.250 us; speedup 1.0000x reference)
//
#include <hip/hip_runtime.h>

// Problem constants (from setup_inputs): bt=4, nv=20000, nf=40000, H=W=256, S=2048
#define BT   4
#define NV   20000
#define NF   40000
#define SMP  2048
#define NPIX (BT * 256 * 256)
#define NVG  (BT * NV)          // 80000 packed vertices
#define NCH  128                // vertex chunks per batch (512 blocks = 2/CU)
#define CHUNK ((NV + NCH - 1) / NCH)   // 157
#define P    8                  // samples per thread in main_k (256 thr * 8 = 2048)
#define RED_BLOCKS 32

// 1) init workspace: visibility array, per-batch flags, reduction acc/cnt.
__global__ void init_k(float* __restrict__ visible,
                       int* __restrict__ flags,
                       float* __restrict__ acc,
                       unsigned int* __restrict__ cnt) {
    int i = blockIdx.x * blockDim.x + threadIdx.x;
    if (i < NVG) visible[i] = 0.0f;
    if (i < BT)  flags[i]   = 0;
    if (i == 0) { acc[0] = 0.0f; cnt[0] = 0u; }
}

// 2) visibility scatter: 4 pixels/thread -> face -> 3 vertices (global ids)
__global__ void vis_k(const int4* __restrict__ p2f,
                      const int* __restrict__ faces,
                      float* __restrict__ visible) {
    int p = blockIdx.x * blockDim.x + threadIdx.x;   // < NPIX/4
    int4 f4 = p2f[p];
    int fs[4] = {f4.x, f4.y, f4.z, f4.w};
    #pragma unroll
    for (int k = 0; k < 4; ++k) {
        int fi = fs[k];
        if (fi >= 0) {
            int b    = fi / NF;          // faces_packed batch
            int base = fi * 3;
            int off  = b * NV;
            visible[faces[base + 0] + off] = 1.0f;   // idempotent racy stores
            visible[faces[base + 1] + off] = 1.0f;
            visible[faces[base + 2] + off] = 1.0f;
        }
    }
}

// 3) pack verts as float4 {-2x,-2y,-2z, |v|^2 or 1e30 if invisible}.
//    q = dot(p, {-2x,-2y,-2z}) + w == |v|^2 - 2<p,v>  (per-sample |p|^2
//    deferred to red_k; argmin invariant to it). Mark batches with >=1
//    invisible vertex.
__global__ void pack_k(const float* __restrict__ verts,
                       const float* __restrict__ visible,
                       float4* __restrict__ packed,
                       int* __restrict__ flags) {
    int i = blockIdx.x * blockDim.x + threadIdx.x;
    if (i >= NVG) return;
    float x = verts[3 * i + 0];
    float y = verts[3 * i + 1];
    float z = verts[3 * i + 2];
    float w;
    if (visible[i] > 0.0f) {
        w = x * x + y * y + z * z;
    } else {
        w = 1e30f;                 // never wins the min (|2<p,v>| << 1e30)
        flags[i / NV] = 1;         // racy idempotent store
    }
    packed[i] = make_float4(-2.0f * x, -2.0f * y, -2.0f * z, w);
}

// 4) main: each thread owns P=8 samples; block stages its vertex chunk in LDS.
//    Per vertex: 1 broadcast LDS read feeds 8 independent 3-fma+fmin chains.
//    Block writes its chunk-min to a private slot -- NO atomics.
__global__ __launch_bounds__(256) void
main_k(const float4* __restrict__ bds,
       const float4* __restrict__ packed,
       float* __restrict__ mnOut) {
    __shared__ float4 sh[256];
    const int b  = blockIdx.z;
    const int c  = blockIdx.x;
    const int v0 = c * CHUNK;
    const int v1 = min(v0 + CHUNK, NV);

    float px[P], py[P], pz[P], mn[P];
    #pragma unroll
    for (int u = 0; u < P; ++u) {
        float4 p = bds[b * SMP + u * 256 + threadIdx.x];
        px[u] = p.x; py[u] = p.y; pz[u] = p.z;
        mn[u] = 3.0e38f;
    }

    const float4* vp = packed + b * NV;
    for (int t = v0; t < v1; t += 256) {
        int idx = t + threadIdx.x;
        if (idx < v1) sh[threadIdx.x] = vp[idx];
        __syncthreads();
        int cnt = min(256, v1 - t);
        #pragma unroll 4
        for (int j = 0; j < cnt; ++j) {
            float4 v = sh[j];                       // broadcast read
            #pragma unroll
            for (int u = 0; u < P; ++u) {
                float q = fmaf(px[u], v.x,
                          fmaf(py[u], v.y,
                          fmaf(pz[u], v.z, v.w)));  // |v|^2 - 2<p,v>
                mn[u] = fminf(mn[u], q);
            }
        }
        __syncthreads();
    }
    float* dst = mnOut + c * (BT * SMP) + b * SMP;
    #pragma unroll
    for (int u = 0; u < P; ++u)
        dst[u * 256 + threadIdx.x] = mn[u];         // coalesced, no atomics
}

// 5) final: min over chunks, add |p|^2, penalty clamp, masked sum.
//    32 blocks; last-done block writes out (threadfence + counter pattern).
__global__ __launch_bounds__(256) void
red_k(const float* __restrict__ mnOut,
      const float4* __restrict__ bds,
      const int* __restrict__ flags,
      float* __restrict__ acc,
      unsigned int* __restrict__ cnt,
      float* __restrict__ out) {
    const int i = blockIdx.x * 256 + threadIdx.x;   // 0..8191 = b*SMP+s
    const int b = i >> 11;
    float4 p = bds[i];
    float v = mnOut[i];                              // chunk 0
    #pragma unroll 8
    for (int c = 1; c < NCH; ++c)
        v = fminf(v, mnOut[c * (BT * SMP) + i]);     // coalesced
    float bs = fmaf(p.x, p.x, fmaf(p.y, p.y, p.z * p.z));
    float mn = v + bs;                               // true min d2
    if (flags[b]) mn = fminf(mn, 1000.0f);           // exact MASK_PENALTY path
    float contrib = mn * p.w;                        // p.w = sample mask

    #pragma unroll
    for (int o = 32; o > 0; o >>= 1) contrib += __shfl_down(contrib, o, 64);
    __shared__ float part[4];
    if ((threadIdx.x & 63) == 0) part[threadIdx.x >> 6] = contrib;
    __syncthreads();
    if (threadIdx.x == 0) {
        float t = part[0] + part[1] + part[2] + part[3];
        atomicAdd(acc, t);
        __threadfence();
        unsigned int n = atomicAdd(cnt, 1u);
        if (n == RED_BLOCKS - 1) {                   // I'm last
            __threadfence();
            out[0] = *((volatile float*)acc) / (float)BT;
        }
    }
}

extern "C" void kernel_launch(void* const* d_in, const int* in_sizes, int n_in,
                              void* d_out, int out_size, void* d_ws, size_t ws_size,
                              hipStream_t stream) {
    const float* verts = (const float*)d_in[0];   // (4,20000,3) f32
    const float* bds   = (const float*)d_in[1];   // (4,2048,4)  f32
    const int*   faces = (const int*)d_in[2];     // (4,40000,3) int
    const int*   p2f   = (const int*)d_in[3];     // (4,256,256,1) int
    float*       out   = (float*)d_out;

    // workspace layout
    char* ws = (char*)d_ws;
    float*  mnOut   = (float*)ws;                                 // 4,194,304 B
    float4* packed  = (float4*)(ws + 4194304);                    // 1,280,000 B
    float*  visible = (float*)(ws + 4194304 + 1280000);           //   320,000 B
    int*    flags   = (int*)(ws + 4194304 + 1280000 + 320000);    //        16 B
    float*  acc     = (float*)(ws + 4194304 + 1280000 + 320016);  //         4 B
    unsigned int* cnt = (unsigned int*)(ws + 4194304 + 1280000 + 320020);

    init_k<<<(NVG + 255) / 256, 256, 0, stream>>>(visible, flags, acc, cnt);
    vis_k<<<(NPIX / 4 + 255) / 256, 256, 0, stream>>>(
        (const int4*)p2f, faces, visible);
    pack_k<<<(NVG + 255) / 256, 256, 0, stream>>>(verts, visible, packed, flags);
    main_k<<<dim3(NCH, 1, BT), 256, 0, stream>>>(
        (const float4*)bds, packed, mnOut);
    red_k<<<RED_BLOCKS, 256, 0, stream>>>(
        mnOut, (const float4*)bds, flags, acc, cnt, out);
}